// Round 1
// baseline (397.432 us; speedup 1.0000x reference)
//
#include <hip/hip_runtime.h>

#define N_NODES 50000
#define N_EDGES 800000
#define DIM     256

// ---------------- GEMM: hidden = x @ W  (fp32, vector ALU) ----------------
#define BM 64
#define BN 64
#define BK 32

__global__ __launch_bounds__(256)
void gemm_xw(const float* __restrict__ X, const float* __restrict__ W,
             float* __restrict__ H) {
    __shared__ float xt[BK][68];   // [k][m], padded
    __shared__ float wt[BK][68];   // [k][n], padded
    const int tid = threadIdx.x;
    const int bm = blockIdx.x * BM;
    const int bn = blockIdx.y * BN;
    const int tx = tid & 15;          // col group (4 cols each)
    const int ty = tid >> 4;          // row group (4 rows each)
    const int lr = tid >> 2;          // 0..63 : x-tile row
    const int c0 = (tid & 3) * 4;     // x-tile col (float4)
    const int wr = tid >> 4;          // 0..15 : W-tile row
    const int wc = (tid & 15) * 4;    // W-tile col (float4)
    const bool mvalid = (bm + lr) < N_NODES;

    float4 acc[4];
#pragma unroll
    for (int i = 0; i < 4; ++i) acc[i] = make_float4(0.f, 0.f, 0.f, 0.f);

    for (int k0 = 0; k0 < DIM; k0 += BK) {
        float4 xv0 = make_float4(0.f,0.f,0.f,0.f), xv1 = xv0;
        if (mvalid) {
            xv0 = *(const float4*)&X[(size_t)(bm + lr) * DIM + k0 + c0];
            xv1 = *(const float4*)&X[(size_t)(bm + lr) * DIM + k0 + c0 + 16];
        }
        const float4 wv0 = *(const float4*)&W[(size_t)(k0 + wr) * DIM + bn + wc];
        const float4 wv1 = *(const float4*)&W[(size_t)(k0 + wr + 16) * DIM + bn + wc];
        __syncthreads();
        xt[c0+0][lr] = xv0.x; xt[c0+1][lr] = xv0.y; xt[c0+2][lr] = xv0.z; xt[c0+3][lr] = xv0.w;
        xt[c0+16][lr] = xv1.x; xt[c0+17][lr] = xv1.y; xt[c0+18][lr] = xv1.z; xt[c0+19][lr] = xv1.w;
        *(float4*)&wt[wr][wc]      = wv0;
        *(float4*)&wt[wr+16][wc]   = wv1;
        __syncthreads();
#pragma unroll
        for (int k = 0; k < BK; ++k) {
            const float4 av = *(const float4*)&xt[k][ty * 4];
            const float4 bv = *(const float4*)&wt[k][tx * 4];
            acc[0].x += av.x*bv.x; acc[0].y += av.x*bv.y; acc[0].z += av.x*bv.z; acc[0].w += av.x*bv.w;
            acc[1].x += av.y*bv.x; acc[1].y += av.y*bv.y; acc[1].z += av.y*bv.z; acc[1].w += av.y*bv.w;
            acc[2].x += av.z*bv.x; acc[2].y += av.z*bv.y; acc[2].z += av.z*bv.z; acc[2].w += av.z*bv.w;
            acc[3].x += av.w*bv.x; acc[3].y += av.w*bv.y; acc[3].z += av.w*bv.z; acc[3].w += av.w*bv.w;
        }
    }
#pragma unroll
    for (int i = 0; i < 4; ++i) {
        const int r = bm + ty * 4 + i;
        if (r < N_NODES)
            *(float4*)&H[(size_t)r * DIM + bn + tx * 4] = acc[i];
    }
}

// ---------------- binning: build destination-CSR ----------------
__global__ __launch_bounds__(256)
void zero_aux(int* __restrict__ cnt, int* __restrict__ cursor) {
    const int i = blockIdx.x * 256 + threadIdx.x;
    if (i < N_NODES) { cnt[i] = 0; cursor[i] = 0; }
}

__global__ __launch_bounds__(256)
void count_edges(const int* __restrict__ rows, int* __restrict__ cnt) {
    const int e = blockIdx.x * 256 + threadIdx.x;
    if (e < N_EDGES) atomicAdd(&cnt[rows[e]], 1);
}

// block-wide exclusive scan over 256 ints (wave64-based)
__device__ __forceinline__ int block_excl_scan_256(int v, int* wsum, int* total) {
    const int lane = threadIdx.x & 63;
    const int wave = threadIdx.x >> 6;
    int x = v;
#pragma unroll
    for (int off = 1; off < 64; off <<= 1) {
        const int y = __shfl_up(x, off, 64);
        if (lane >= off) x += y;
    }
    if (lane == 63) wsum[wave] = x;
    __syncthreads();
    if (threadIdx.x == 0) {
        int s = 0;
#pragma unroll
        for (int w = 0; w < 4; ++w) { const int t = wsum[w]; wsum[w] = s; s += t; }
        *total = s;
    }
    __syncthreads();
    return wsum[wave] + x - v;
}

__global__ __launch_bounds__(256)
void scan_blocks(const int* __restrict__ cnt, int* __restrict__ offs,
                 int* __restrict__ bsum) {
    __shared__ int wsum[4];
    __shared__ int total;
    const int i = blockIdx.x * 256 + threadIdx.x;
    const int v = (i < N_NODES) ? cnt[i] : 0;
    const int excl = block_excl_scan_256(v, wsum, &total);
    if (i < N_NODES) offs[i] = excl;
    if (threadIdx.x == 0) bsum[blockIdx.x] = total;
}

#define NBLK_NODES 196   // ceil(50000/256)

__global__ __launch_bounds__(256)
void scan_top(int* __restrict__ bsum) {
    __shared__ int wsum[4];
    __shared__ int total;
    const int t = threadIdx.x;
    const int v = (t < NBLK_NODES) ? bsum[t] : 0;
    const int excl = block_excl_scan_256(v, wsum, &total);
    if (t < NBLK_NODES) bsum[t] = excl;
}

__global__ __launch_bounds__(256)
void scan_add(int* __restrict__ offs, const int* __restrict__ bsum) {
    const int i = blockIdx.x * 256 + threadIdx.x;
    if (i < N_NODES) offs[i] += bsum[blockIdx.x];
    if (i == 0) offs[N_NODES] = N_EDGES;
}

__global__ __launch_bounds__(256)
void fill_edges(const int* __restrict__ rows, const int* __restrict__ cols,
                const float* __restrict__ vals, const int* __restrict__ offs,
                int* __restrict__ cursor, int* __restrict__ pcol,
                float* __restrict__ pval) {
    const int e = blockIdx.x * 256 + threadIdx.x;
    if (e >= N_EDGES) return;
    const int r = rows[e];
    const int p = atomicAdd(&cursor[r], 1);
    const int idx = offs[r] + p;
    pcol[idx] = cols[e];
    pval[idx] = vals[e];
}

// ---------------- SpMM: out[r] = sum_e val*hidden[col] + b  (1 wave / row) ----------------
__global__ __launch_bounds__(256)
void spmm(const float* __restrict__ hidden, const int* __restrict__ offs,
          const int* __restrict__ pcol, const float* __restrict__ pval,
          const float* __restrict__ bias, float* __restrict__ out) {
    const int row  = blockIdx.x * 4 + (threadIdx.x >> 6);
    const int lane = threadIdx.x & 63;
    if (row >= N_NODES) return;
    const int beg = offs[row];
    const int end = offs[row + 1];
    float4 acc = make_float4(0.f, 0.f, 0.f, 0.f);
    for (int i = beg; i < end; ++i) {
        const int   c = pcol[i];
        const float v = pval[i];
        const float4 h = *(const float4*)&hidden[(size_t)c * DIM + lane * 4];
        acc.x += v * h.x; acc.y += v * h.y; acc.z += v * h.z; acc.w += v * h.w;
    }
    const float4 bb = *(const float4*)&bias[lane * 4];
    acc.x += bb.x; acc.y += bb.y; acc.z += bb.z; acc.w += bb.w;
    *(float4*)&out[(size_t)row * DIM + lane * 4] = acc;
}

// ---------------- launch ----------------
extern "C" void kernel_launch(void* const* d_in, const int* in_sizes, int n_in,
                              void* d_out, int out_size, void* d_ws, size_t ws_size,
                              hipStream_t stream) {
    const float* x        = (const float*)d_in[0];
    const int*   adj_rows = (const int*)d_in[1];
    const int*   adj_cols = (const int*)d_in[2];
    const float* adj_vals = (const float*)d_in[3];
    const float* W        = (const float*)d_in[4];
    const float* b        = (const float*)d_in[5];
    float*       out      = (float*)d_out;

    char* ws = (char*)d_ws;
    size_t off = 0;
    auto alloc = [&](size_t bytes) {
        void* p = ws + off;
        off = (off + bytes + 255) & ~(size_t)255;
        return p;
    };
    float* hidden = (float*)alloc((size_t)N_NODES * DIM * sizeof(float)); // 51.2 MB
    int*   offs   = (int*)  alloc((N_NODES + 1) * sizeof(int));
    int*   cnt    = (int*)  alloc(N_NODES * sizeof(int));
    int*   cursor = (int*)  alloc(N_NODES * sizeof(int));
    int*   bsum   = (int*)  alloc(256 * sizeof(int));
    int*   pcol   = (int*)  alloc((size_t)N_EDGES * sizeof(int));
    float* pval   = (float*)alloc((size_t)N_EDGES * sizeof(float));

    // GEMM: hidden = x @ W
    dim3 ggrid((N_NODES + BM - 1) / BM, DIM / BN);
    gemm_xw<<<ggrid, 256, 0, stream>>>(x, W, hidden);

    // binning
    zero_aux<<<NBLK_NODES, 256, 0, stream>>>(cnt, cursor);
    count_edges<<<(N_EDGES + 255) / 256, 256, 0, stream>>>(adj_rows, cnt);
    scan_blocks<<<NBLK_NODES, 256, 0, stream>>>(cnt, offs, bsum);
    scan_top<<<1, 256, 0, stream>>>(bsum);
    scan_add<<<NBLK_NODES, 256, 0, stream>>>(offs, bsum);
    fill_edges<<<(N_EDGES + 255) / 256, 256, 0, stream>>>(
        adj_rows, adj_cols, adj_vals, offs, cursor, pcol, pval);

    // SpMM + bias
    spmm<<<(N_NODES + 3) / 4, 256, 0, stream>>>(hidden, offs, pcol, pval, b, out);
}

// Round 3
// 333.594 us; speedup vs baseline: 1.1914x; 1.1914x over previous
//
#include <hip/hip_runtime.h>

#define N_NODES 50000
#define N_EDGES 800000
#define DIM     256

__device__ __forceinline__ unsigned short f2bf(float f) {
    unsigned u = __float_as_uint(f);
    unsigned r = (u + 0x7fffu + ((u >> 16) & 1u)) >> 16;
    return (unsigned short)r;
}
__device__ __forceinline__ float bf2f(unsigned short h) {
    return __uint_as_float((unsigned)h << 16);
}

// ---------------- GEMM: hidden = x @ W  (fp32 VALU, 128x128 tile, 8x8 micro) ----------------
#define GBM 128
#define GBN 128
#define GBK 16

__global__ __launch_bounds__(256)
void gemm_xw(const float* __restrict__ X, const float* __restrict__ W,
             unsigned short* __restrict__ Hb) {
    __shared__ float xt[GBK][GBM + 4];   // [k][m]
    __shared__ float wt[GBK][GBN + 4];   // [k][n]
    const int tid = threadIdx.x;
    const int bm = blockIdx.x * GBM;
    const int bn = blockIdx.y * GBN;
    const int tx = tid & 15;
    const int ty = tid >> 4;

    const int xrow = tid >> 1;                // 0..127
    const int xc0  = (tid & 1) * 8;           // cols xc0..xc0+7
    const bool mvalid = (bm + xrow) < N_NODES;
    const int wkr = tid >> 4;
    const int wc0 = (tid & 15) * 8;

    float4 acc[2][2][4];
#pragma unroll
    for (int a = 0; a < 2; ++a)
#pragma unroll
        for (int b2 = 0; b2 < 2; ++b2)
#pragma unroll
            for (int i = 0; i < 4; ++i) acc[a][b2][i] = make_float4(0.f, 0.f, 0.f, 0.f);

    for (int k0 = 0; k0 < DIM; k0 += GBK) {
        float4 xv0 = make_float4(0.f,0.f,0.f,0.f), xv1 = xv0;
        if (mvalid) {
            xv0 = *(const float4*)&X[(size_t)(bm + xrow) * DIM + k0 + xc0];
            xv1 = *(const float4*)&X[(size_t)(bm + xrow) * DIM + k0 + xc0 + 4];
        }
        const float4 wv0 = *(const float4*)&W[(size_t)(k0 + wkr) * DIM + bn + wc0];
        const float4 wv1 = *(const float4*)&W[(size_t)(k0 + wkr) * DIM + bn + wc0 + 4];
        __syncthreads();
        xt[xc0+0][xrow] = xv0.x; xt[xc0+1][xrow] = xv0.y; xt[xc0+2][xrow] = xv0.z; xt[xc0+3][xrow] = xv0.w;
        xt[xc0+4][xrow] = xv1.x; xt[xc0+5][xrow] = xv1.y; xt[xc0+6][xrow] = xv1.z; xt[xc0+7][xrow] = xv1.w;
        *(float4*)&wt[wkr][wc0]     = wv0;
        *(float4*)&wt[wkr][wc0 + 4] = wv1;
        __syncthreads();
#pragma unroll
        for (int k = 0; k < GBK; ++k) {
            const float4 a0 = *(const float4*)&xt[k][ty * 4];
            const float4 a1 = *(const float4*)&xt[k][64 + ty * 4];
            const float4 b0 = *(const float4*)&wt[k][tx * 4];
            const float4 b1 = *(const float4*)&wt[k][64 + tx * 4];
            const float am[2][4] = {{a0.x,a0.y,a0.z,a0.w},{a1.x,a1.y,a1.z,a1.w}};
            const float4 bn2[2] = {b0, b1};
#pragma unroll
            for (int a = 0; a < 2; ++a)
#pragma unroll
                for (int b2 = 0; b2 < 2; ++b2)
#pragma unroll
                    for (int i = 0; i < 4; ++i) {
                        acc[a][b2][i].x += am[a][i] * bn2[b2].x;
                        acc[a][b2][i].y += am[a][i] * bn2[b2].y;
                        acc[a][b2][i].z += am[a][i] * bn2[b2].z;
                        acc[a][b2][i].w += am[a][i] * bn2[b2].w;
                    }
        }
    }
#pragma unroll
    for (int a = 0; a < 2; ++a)
#pragma unroll
        for (int i = 0; i < 4; ++i) {
            const int r = bm + a * 64 + ty * 4 + i;
            if (r >= N_NODES) continue;
#pragma unroll
            for (int b2 = 0; b2 < 2; ++b2) {
                const float4 v = acc[a][b2][i];
                ushort4 h;
                h.x = f2bf(v.x); h.y = f2bf(v.y); h.z = f2bf(v.z); h.w = f2bf(v.w);
                *(ushort4*)&Hb[(size_t)r * DIM + bn + b2 * 64 + tx * 4] = h;
            }
        }
}

// ---------------- binning: build destination-CSR ----------------
__global__ __launch_bounds__(256)
void zero_aux(int* __restrict__ cnt, int* __restrict__ cursor) {
    const int i = blockIdx.x * 256 + threadIdx.x;
    if (i < N_NODES) { cnt[i] = 0; cursor[i] = 0; }
}

__global__ __launch_bounds__(256)
void count_edges(const int* __restrict__ rows, int* __restrict__ cnt) {
    const int e = blockIdx.x * 256 + threadIdx.x;
    if (e < N_EDGES) atomicAdd(&cnt[rows[e]], 1);
}

__device__ __forceinline__ int block_excl_scan_256(int v, int* wsum, int* total) {
    const int lane = threadIdx.x & 63;
    const int wave = threadIdx.x >> 6;
    int x = v;
#pragma unroll
    for (int off = 1; off < 64; off <<= 1) {
        const int y = __shfl_up(x, off, 64);
        if (lane >= off) x += y;
    }
    if (lane == 63) wsum[wave] = x;
    __syncthreads();
    if (threadIdx.x == 0) {
        int s = 0;
#pragma unroll
        for (int w = 0; w < 4; ++w) { const int t = wsum[w]; wsum[w] = s; s += t; }
        *total = s;
    }
    __syncthreads();
    return wsum[wave] + x - v;
}

__global__ __launch_bounds__(256)
void scan_blocks(const int* __restrict__ cnt, int* __restrict__ offs,
                 int* __restrict__ bsum) {
    __shared__ int wsum[4];
    __shared__ int total;
    const int i = blockIdx.x * 256 + threadIdx.x;
    const int v = (i < N_NODES) ? cnt[i] : 0;
    const int excl = block_excl_scan_256(v, wsum, &total);
    if (i < N_NODES) offs[i] = excl;
    if (threadIdx.x == 0) bsum[blockIdx.x] = total;
}

#define NBLK_NODES 196   // ceil(50000/256)

__global__ __launch_bounds__(256)
void scan_top(int* __restrict__ bsum) {
    __shared__ int wsum[4];
    __shared__ int total;
    const int t = threadIdx.x;
    const int v = (t < NBLK_NODES) ? bsum[t] : 0;
    const int excl = block_excl_scan_256(v, wsum, &total);
    if (t < NBLK_NODES) bsum[t] = excl;
}

__global__ __launch_bounds__(256)
void scan_add(int* __restrict__ offs, const int* __restrict__ bsum) {
    const int i = blockIdx.x * 256 + threadIdx.x;
    if (i < N_NODES) offs[i] += bsum[blockIdx.x];
    if (i == 0) offs[N_NODES] = N_EDGES;
}

__global__ __launch_bounds__(256)
void fill_edges(const int* __restrict__ rows, const int* __restrict__ cols,
                const float* __restrict__ vals, const int* __restrict__ offs,
                int* __restrict__ cursor, int2* __restrict__ pe) {
    const int e = blockIdx.x * 256 + threadIdx.x;
    if (e >= N_EDGES) return;
    const int r = rows[e];
    const int p = atomicAdd(&cursor[r], 1);
    pe[offs[r] + p] = make_int2(cols[e], __float_as_int(vals[e]));
}

// ---------------- SpMM: out[r] = sum_e val * hidden_bf16[col] + b ----------------
__global__ __launch_bounds__(256)
void spmm(const unsigned short* __restrict__ Hb, const int* __restrict__ offs,
          const int2* __restrict__ pe, const float* __restrict__ bias,
          float* __restrict__ out) {
    const int row  = blockIdx.x * 4 + (threadIdx.x >> 6);
    const int lane = threadIdx.x & 63;
    if (row >= N_NODES) return;
    const int beg = offs[row];
    const int end = offs[row + 1];
    float4 acc = make_float4(0.f, 0.f, 0.f, 0.f);
    int i = beg;
    for (; i + 3 < end; i += 4) {
        const int2 e0 = pe[i], e1 = pe[i+1], e2 = pe[i+2], e3 = pe[i+3];
        const ushort4 h0 = *(const ushort4*)&Hb[(size_t)e0.x * DIM + lane * 4];
        const ushort4 h1 = *(const ushort4*)&Hb[(size_t)e1.x * DIM + lane * 4];
        const ushort4 h2 = *(const ushort4*)&Hb[(size_t)e2.x * DIM + lane * 4];
        const ushort4 h3 = *(const ushort4*)&Hb[(size_t)e3.x * DIM + lane * 4];
        const float v0 = __int_as_float(e0.y), v1 = __int_as_float(e1.y);
        const float v2 = __int_as_float(e2.y), v3 = __int_as_float(e3.y);
        acc.x += v0 * bf2f(h0.x) + v1 * bf2f(h1.x) + v2 * bf2f(h2.x) + v3 * bf2f(h3.x);
        acc.y += v0 * bf2f(h0.y) + v1 * bf2f(h1.y) + v2 * bf2f(h2.y) + v3 * bf2f(h3.y);
        acc.z += v0 * bf2f(h0.z) + v1 * bf2f(h1.z) + v2 * bf2f(h2.z) + v3 * bf2f(h3.z);
        acc.w += v0 * bf2f(h0.w) + v1 * bf2f(h1.w) + v2 * bf2f(h2.w) + v3 * bf2f(h3.w);
    }
    for (; i < end; ++i) {
        const int2 e0 = pe[i];
        const ushort4 h0 = *(const ushort4*)&Hb[(size_t)e0.x * DIM + lane * 4];
        const float v0 = __int_as_float(e0.y);
        acc.x += v0 * bf2f(h0.x);
        acc.y += v0 * bf2f(h0.y);
        acc.z += v0 * bf2f(h0.z);
        acc.w += v0 * bf2f(h0.w);
    }
    const float4 bb = *(const float4*)&bias[lane * 4];
    acc.x += bb.x; acc.y += bb.y; acc.z += bb.z; acc.w += bb.w;
    *(float4*)&out[(size_t)row * DIM + lane * 4] = acc;
}

// ---------------- launch ----------------
extern "C" void kernel_launch(void* const* d_in, const int* in_sizes, int n_in,
                              void* d_out, int out_size, void* d_ws, size_t ws_size,
                              hipStream_t stream) {
    const float* x        = (const float*)d_in[0];
    const int*   adj_rows = (const int*)d_in[1];
    const int*   adj_cols = (const int*)d_in[2];
    const float* adj_vals = (const float*)d_in[3];
    const float* W        = (const float*)d_in[4];
    const float* b        = (const float*)d_in[5];
    float*       out      = (float*)d_out;

    char* ws = (char*)d_ws;
    size_t off = 0;
    auto alloc = [&](size_t bytes) {
        void* p = ws + off;
        off = (off + bytes + 255) & ~(size_t)255;
        return p;
    };
    unsigned short* hiddenb = (unsigned short*)alloc((size_t)N_NODES * DIM * sizeof(unsigned short)); // 25.6 MB
    int*   offs   = (int*)  alloc((N_NODES + 1) * sizeof(int));
    int*   cnt    = (int*)  alloc(N_NODES * sizeof(int));
    int*   cursor = (int*)  alloc(N_NODES * sizeof(int));
    int*   bsum   = (int*)  alloc(256 * sizeof(int));
    int2*  pe     = (int2*) alloc((size_t)N_EDGES * sizeof(int2));  // 6.4 MB

    // GEMM: hidden = x @ W  (bf16 output)
    dim3 ggrid((N_NODES + GBM - 1) / GBM, DIM / GBN);
    gemm_xw<<<ggrid, 256, 0, stream>>>(x, W, hiddenb);

    // binning
    zero_aux<<<NBLK_NODES, 256, 0, stream>>>(cnt, cursor);
    count_edges<<<(N_EDGES + 255) / 256, 256, 0, stream>>>(adj_rows, cnt);
    scan_blocks<<<NBLK_NODES, 256, 0, stream>>>(cnt, offs, bsum);
    scan_top<<<1, 256, 0, stream>>>(bsum);
    scan_add<<<NBLK_NODES, 256, 0, stream>>>(offs, bsum);
    fill_edges<<<(N_EDGES + 255) / 256, 256, 0, stream>>>(
        adj_rows, adj_cols, adj_vals, offs, cursor, pe);

    // SpMM + bias
    spmm<<<(N_NODES + 3) / 4, 256, 0, stream>>>(hiddenb, offs, pe, b, out);
}

// Round 4
// 266.457 us; speedup vs baseline: 1.4915x; 1.2520x over previous
//
#include <hip/hip_runtime.h>

#define N_NODES 50000
#define N_EDGES 800000
#define DIM     256
#define N_STRIPS 3125   // 50000 / 16

typedef __attribute__((ext_vector_type(8))) short bf16x8;
typedef __attribute__((ext_vector_type(4))) float f32x4;

__device__ __forceinline__ unsigned short f2bf(float f) {
    unsigned u = __float_as_uint(f);
    unsigned r = (u + 0x7fffu + ((u >> 16) & 1u)) >> 16;
    return (unsigned short)r;
}
__device__ __forceinline__ float bf2f(unsigned short h) {
    return __uint_as_float((unsigned)h << 16);
}

// ---------------- prep: Wt[n][k] = bf16(W[k][n]) ----------------
__global__ __launch_bounds__(256)
void wtrans(const float* __restrict__ W, unsigned short* __restrict__ Wt) {
    const int n = blockIdx.x;
    const int k = threadIdx.x;
    Wt[n * DIM + k] = f2bf(W[(size_t)k * DIM + n]);
}

// ---------------- GEMM: hidden_bf16 = bf16(x) @ bf16(W) via MFMA ----------------
// One 512-thread block per CU (128 KB LDS for swizzled W^T). Each wave owns a
// 16-row strip of x; A loaded direct from global fp32 (all 16 float4 up-front),
// B from LDS. XOR swizzle: kbyte ^= (n&7)<<4 keeps ds_read_b128 conflict-free.
__global__ __launch_bounds__(512, 2)
void gemm_mfma(const float* __restrict__ X, const unsigned short* __restrict__ Wt,
               unsigned short* __restrict__ Hb) {
    __shared__ unsigned short wl[DIM * DIM];   // 128 KB, [n][k] swizzled
    const int tid = threadIdx.x;

    // fill LDS from global Wt (16B chunks, swizzled dest)
    {
        const uint4* src = (const uint4*)Wt;   // 8192 chunks of 16B
#pragma unroll
        for (int i = 0; i < 16; ++i) {
            const int c   = i * 512 + tid;
            const int row = c >> 5;                 // n (row = 512B)
            const int kb  = (c & 31) * 16;          // byte offset within row
            const int dst = row * 512 + (kb ^ ((row & 7) << 4));
            *(uint4*)((char*)wl + dst) = src[c];
        }
    }
    __syncthreads();

    const int wid   = tid >> 6;
    const int lane  = tid & 63;
    const int strip = blockIdx.x * 8 + wid;
    if (strip >= N_STRIPS) return;

    const int r0   = strip * 16;
    const int arow = lane & 15;        // A row / C col index
    const int kgrp = lane >> 4;        // 0..3 : k-octet selector
    const float* xrow = X + (size_t)(r0 + arow) * DIM + kgrp * 8;

    // issue ALL A loads up-front (16 KB/wave): hides HBM latency at 2 waves/SIMD
    float4 araw[8][2];
#pragma unroll
    for (int ks = 0; ks < 8; ++ks) {
        araw[ks][0] = *(const float4*)(xrow + ks * 32);
        araw[ks][1] = *(const float4*)(xrow + ks * 32 + 4);
    }

    f32x4 acc[16];
#pragma unroll
    for (int nt = 0; nt < 16; ++nt) acc[nt] = f32x4{0.f, 0.f, 0.f, 0.f};

    const int swz = (arow & 7) << 4;   // loop-invariant XOR term (n&7 == arow&7)
#pragma unroll
    for (int ks = 0; ks < 8; ++ks) {
        bf16x8 a;
        a[0] = (short)f2bf(araw[ks][0].x); a[1] = (short)f2bf(araw[ks][0].y);
        a[2] = (short)f2bf(araw[ks][0].z); a[3] = (short)f2bf(araw[ks][0].w);
        a[4] = (short)f2bf(araw[ks][1].x); a[5] = (short)f2bf(araw[ks][1].y);
        a[6] = (short)f2bf(araw[ks][1].z); a[7] = (short)f2bf(araw[ks][1].w);
        const int kb = ((ks * 32 + kgrp * 8) * 2) ^ swz;   // swizzled byte offset in row
#pragma unroll
        for (int nt = 0; nt < 16; ++nt) {
            const int n = nt * 16 + arow;
            const bf16x8 b = *(const bf16x8*)((const char*)wl + n * 512 + kb);
            acc[nt] = __builtin_amdgcn_mfma_f32_16x16x32_bf16(a, b, acc[nt], 0, 0, 0);
        }
    }

    // epilogue: C[row=(lane>>4)*4+q][col=lane&15] per 16-col tile
    const int crow0 = r0 + kgrp * 4;
#pragma unroll
    for (int nt = 0; nt < 16; ++nt) {
#pragma unroll
        for (int q = 0; q < 4; ++q) {
            Hb[(size_t)(crow0 + q) * DIM + nt * 16 + arow] = f2bf(acc[nt][q]);
        }
    }
}

// ---------------- binning: build destination-CSR ----------------
__global__ __launch_bounds__(256)
void zero_aux(int* __restrict__ cnt, int* __restrict__ cursor) {
    const int i = blockIdx.x * 256 + threadIdx.x;
    if (i < N_NODES) { cnt[i] = 0; cursor[i] = 0; }
}

__global__ __launch_bounds__(256)
void count_edges(const int* __restrict__ rows, int* __restrict__ cnt) {
    const int e = blockIdx.x * 256 + threadIdx.x;
    if (e < N_EDGES) atomicAdd(&cnt[rows[e]], 1);
}

__device__ __forceinline__ int block_excl_scan_256(int v, int* wsum, int* total) {
    const int lane = threadIdx.x & 63;
    const int wave = threadIdx.x >> 6;
    int x = v;
#pragma unroll
    for (int off = 1; off < 64; off <<= 1) {
        const int y = __shfl_up(x, off, 64);
        if (lane >= off) x += y;
    }
    if (lane == 63) wsum[wave] = x;
    __syncthreads();
    if (threadIdx.x == 0) {
        int s = 0;
#pragma unroll
        for (int w = 0; w < 4; ++w) { const int t = wsum[w]; wsum[w] = s; s += t; }
        *total = s;
    }
    __syncthreads();
    return wsum[wave] + x - v;
}

__global__ __launch_bounds__(256)
void scan_blocks(const int* __restrict__ cnt, int* __restrict__ offs,
                 int* __restrict__ bsum) {
    __shared__ int wsum[4];
    __shared__ int total;
    const int i = blockIdx.x * 256 + threadIdx.x;
    const int v = (i < N_NODES) ? cnt[i] : 0;
    const int excl = block_excl_scan_256(v, wsum, &total);
    if (i < N_NODES) offs[i] = excl;
    if (threadIdx.x == 0) bsum[blockIdx.x] = total;
}

#define NBLK_NODES 196   // ceil(50000/256)

__global__ __launch_bounds__(256)
void scan_top(int* __restrict__ bsum) {
    __shared__ int wsum[4];
    __shared__ int total;
    const int t = threadIdx.x;
    const int v = (t < NBLK_NODES) ? bsum[t] : 0;
    const int excl = block_excl_scan_256(v, wsum, &total);
    if (t < NBLK_NODES) bsum[t] = excl;
}

__global__ __launch_bounds__(256)
void scan_add(int* __restrict__ offs, const int* __restrict__ bsum) {
    const int i = blockIdx.x * 256 + threadIdx.x;
    if (i < N_NODES) offs[i] += bsum[blockIdx.x];
    if (i == 0) offs[N_NODES] = N_EDGES;
}

__global__ __launch_bounds__(256)
void fill_edges(const int* __restrict__ rows, const int* __restrict__ cols,
                const float* __restrict__ vals, const int* __restrict__ offs,
                int* __restrict__ cursor, int2* __restrict__ pe) {
    const int e = blockIdx.x * 256 + threadIdx.x;
    if (e >= N_EDGES) return;
    const int r = rows[e];
    const int p = atomicAdd(&cursor[r], 1);
    pe[offs[r] + p] = make_int2(cols[e], __float_as_int(vals[e]));
}

// ---------------- SpMM: out[r] = sum_e val * hidden_bf16[col] + b ----------------
__global__ __launch_bounds__(256)
void spmm(const unsigned short* __restrict__ Hb, const int* __restrict__ offs,
          const int2* __restrict__ pe, const float* __restrict__ bias,
          float* __restrict__ out) {
    const int row  = blockIdx.x * 4 + (threadIdx.x >> 6);
    const int lane = threadIdx.x & 63;
    if (row >= N_NODES) return;
    const int beg = offs[row];
    const int end = offs[row + 1];
    float4 acc = make_float4(0.f, 0.f, 0.f, 0.f);
    int i = beg;
    for (; i + 3 < end; i += 4) {
        const int2 e0 = pe[i], e1 = pe[i+1], e2 = pe[i+2], e3 = pe[i+3];
        const ushort4 h0 = *(const ushort4*)&Hb[(size_t)e0.x * DIM + lane * 4];
        const ushort4 h1 = *(const ushort4*)&Hb[(size_t)e1.x * DIM + lane * 4];
        const ushort4 h2 = *(const ushort4*)&Hb[(size_t)e2.x * DIM + lane * 4];
        const ushort4 h3 = *(const ushort4*)&Hb[(size_t)e3.x * DIM + lane * 4];
        const float v0 = __int_as_float(e0.y), v1 = __int_as_float(e1.y);
        const float v2 = __int_as_float(e2.y), v3 = __int_as_float(e3.y);
        acc.x += v0 * bf2f(h0.x) + v1 * bf2f(h1.x) + v2 * bf2f(h2.x) + v3 * bf2f(h3.x);
        acc.y += v0 * bf2f(h0.y) + v1 * bf2f(h1.y) + v2 * bf2f(h2.y) + v3 * bf2f(h3.y);
        acc.z += v0 * bf2f(h0.z) + v1 * bf2f(h1.z) + v2 * bf2f(h2.z) + v3 * bf2f(h3.z);
        acc.w += v0 * bf2f(h0.w) + v1 * bf2f(h1.w) + v2 * bf2f(h2.w) + v3 * bf2f(h3.w);
    }
    for (; i < end; ++i) {
        const int2 e0 = pe[i];
        const ushort4 h0 = *(const ushort4*)&Hb[(size_t)e0.x * DIM + lane * 4];
        const float v0 = __int_as_float(e0.y);
        acc.x += v0 * bf2f(h0.x);
        acc.y += v0 * bf2f(h0.y);
        acc.z += v0 * bf2f(h0.z);
        acc.w += v0 * bf2f(h0.w);
    }
    const float4 bb = *(const float4*)&bias[lane * 4];
    acc.x += bb.x; acc.y += bb.y; acc.z += bb.z; acc.w += bb.w;
    *(float4*)&out[(size_t)row * DIM + lane * 4] = acc;
}

// ---------------- launch ----------------
extern "C" void kernel_launch(void* const* d_in, const int* in_sizes, int n_in,
                              void* d_out, int out_size, void* d_ws, size_t ws_size,
                              hipStream_t stream) {
    const float* x        = (const float*)d_in[0];
    const int*   adj_rows = (const int*)d_in[1];
    const int*   adj_cols = (const int*)d_in[2];
    const float* adj_vals = (const float*)d_in[3];
    const float* W        = (const float*)d_in[4];
    const float* b        = (const float*)d_in[5];
    float*       out      = (float*)d_out;

    char* ws = (char*)d_ws;
    size_t off = 0;
    auto alloc = [&](size_t bytes) {
        void* p = ws + off;
        off = (off + bytes + 255) & ~(size_t)255;
        return p;
    };
    unsigned short* hiddenb = (unsigned short*)alloc((size_t)N_NODES * DIM * sizeof(unsigned short)); // 25.6 MB
    unsigned short* Wt      = (unsigned short*)alloc((size_t)DIM * DIM * sizeof(unsigned short));     // 128 KB
    int*   offs   = (int*)  alloc((N_NODES + 1) * sizeof(int));
    int*   cnt    = (int*)  alloc(N_NODES * sizeof(int));
    int*   cursor = (int*)  alloc(N_NODES * sizeof(int));
    int*   bsum   = (int*)  alloc(256 * sizeof(int));
    int2*  pe     = (int2*) alloc((size_t)N_EDGES * sizeof(int2));  // 6.4 MB

    // prep: W -> W^T bf16
    wtrans<<<DIM, 256, 0, stream>>>(W, Wt);

    // GEMM: hidden = bf16(x) @ bf16(W)  (MFMA)
    gemm_mfma<<<(N_STRIPS + 7) / 8, 512, 0, stream>>>(x, Wt, hiddenb);

    // binning
    zero_aux<<<NBLK_NODES, 256, 0, stream>>>(cnt, cursor);
    count_edges<<<(N_EDGES + 255) / 256, 256, 0, stream>>>(adj_rows, cnt);
    scan_blocks<<<NBLK_NODES, 256, 0, stream>>>(cnt, offs, bsum);
    scan_top<<<1, 256, 0, stream>>>(bsum);
    scan_add<<<NBLK_NODES, 256, 0, stream>>>(offs, bsum);
    fill_edges<<<(N_EDGES + 255) / 256, 256, 0, stream>>>(
        adj_rows, adj_cols, adj_vals, offs, cursor, pe);

    // SpMM + bias
    spmm<<<(N_NODES + 3) / 4, 256, 0, stream>>>(hiddenb, offs, pe, b, out);
}

// Round 5
// 264.923 us; speedup vs baseline: 1.5002x; 1.0058x over previous
//
#include <hip/hip_runtime.h>

#define N_NODES 50000
#define N_EDGES 800000
#define DIM     256
#define STRIPS32 1563   // ceil(50000/32)

typedef __attribute__((ext_vector_type(8))) short bf16x8;
typedef __attribute__((ext_vector_type(4))) float f32x4;

__device__ __forceinline__ unsigned short f2bf(float f) {
    unsigned u = __float_as_uint(f);
    unsigned r = (u + 0x7fffu + ((u >> 16) & 1u)) >> 16;
    return (unsigned short)r;
}
__device__ __forceinline__ float bf2f(unsigned short h) {
    return __uint_as_float((unsigned)h << 16);
}

// ---------------- prep: Wt[n][k] = bf16(W[k][n]) ----------------
__global__ __launch_bounds__(256)
void wtrans(const float* __restrict__ W, unsigned short* __restrict__ Wt) {
    const int n = blockIdx.x;
    const int k = threadIdx.x;
    Wt[n * DIM + k] = f2bf(W[(size_t)k * DIM + n]);
}

// ---------------- GEMM: hidden_bf16 = bf16(x) @ bf16(W) via MFMA ----------------
// 512-thread block, 128 KB LDS-resident swizzled W^T. Each wave owns a 32-row
// strip: 2 A-fragments share every B ds_read (2:1 MFMA:ds ratio). A loads are
// software-pipelined (ks+1 issued before ks's MFMAs).
__global__ __launch_bounds__(512, 2)
void gemm_mfma(const float* __restrict__ X, const unsigned short* __restrict__ Wt,
               unsigned short* __restrict__ Hb) {
    __shared__ unsigned short wl[DIM * DIM];   // 128 KB, [n][k] swizzled
    const int tid = threadIdx.x;
    {
        const uint4* src = (const uint4*)Wt;   // 8192 chunks of 16B
#pragma unroll
        for (int i = 0; i < 16; ++i) {
            const int c   = i * 512 + tid;
            const int row = c >> 5;
            const int kb  = (c & 31) * 16;
            const int dst = row * 512 + (kb ^ ((row & 7) << 4));
            *(uint4*)((char*)wl + dst) = src[c];
        }
    }
    __syncthreads();

    const int wid   = tid >> 6;
    const int lane  = tid & 63;
    const int strip = blockIdx.x * 8 + wid;
    if (strip >= STRIPS32) return;

    const int r0   = strip * 32;
    const int arow = lane & 15;
    const int kgrp = lane >> 4;
    const int ra = r0 + arow;
    const int rb = r0 + 16 + arow;
    const float* xa = X + (size_t)(ra < N_NODES ? ra : N_NODES - 1) * DIM + kgrp * 8;
    const float* xb = X + (size_t)(rb < N_NODES ? rb : N_NODES - 1) * DIM + kgrp * 8;

    f32x4 acc[2][16];
#pragma unroll
    for (int h = 0; h < 2; ++h)
#pragma unroll
        for (int nt = 0; nt < 16; ++nt) acc[h][nt] = f32x4{0.f, 0.f, 0.f, 0.f};

    const int swz = (arow & 7) << 4;

    float4 pa0 = *(const float4*)(xa);
    float4 pa1 = *(const float4*)(xa + 4);
    float4 pb0 = *(const float4*)(xb);
    float4 pb1 = *(const float4*)(xb + 4);

#pragma unroll
    for (int ks = 0; ks < 8; ++ks) {
        bf16x8 a0, a1;
        a0[0] = (short)f2bf(pa0.x); a0[1] = (short)f2bf(pa0.y);
        a0[2] = (short)f2bf(pa0.z); a0[3] = (short)f2bf(pa0.w);
        a0[4] = (short)f2bf(pa1.x); a0[5] = (short)f2bf(pa1.y);
        a0[6] = (short)f2bf(pa1.z); a0[7] = (short)f2bf(pa1.w);
        a1[0] = (short)f2bf(pb0.x); a1[1] = (short)f2bf(pb0.y);
        a1[2] = (short)f2bf(pb0.z); a1[3] = (short)f2bf(pb0.w);
        a1[4] = (short)f2bf(pb1.x); a1[5] = (short)f2bf(pb1.y);
        a1[6] = (short)f2bf(pb1.z); a1[7] = (short)f2bf(pb1.w);
        if (ks < 7) {
            pa0 = *(const float4*)(xa + (ks + 1) * 32);
            pa1 = *(const float4*)(xa + (ks + 1) * 32 + 4);
            pb0 = *(const float4*)(xb + (ks + 1) * 32);
            pb1 = *(const float4*)(xb + (ks + 1) * 32 + 4);
        }
        const int kb = ((ks * 32 + kgrp * 8) * 2) ^ swz;
#pragma unroll
        for (int nt = 0; nt < 16; ++nt) {
            const int n = nt * 16 + arow;
            const bf16x8 b = *(const bf16x8*)((const char*)wl + n * 512 + kb);
            acc[0][nt] = __builtin_amdgcn_mfma_f32_16x16x32_bf16(a0, b, acc[0][nt], 0, 0, 0);
            acc[1][nt] = __builtin_amdgcn_mfma_f32_16x16x32_bf16(a1, b, acc[1][nt], 0, 0, 0);
        }
    }

    // epilogue: C[row=(lane>>4)*4+q][col=lane&15] per 16x16 tile, 2 row-halves
#pragma unroll
    for (int h = 0; h < 2; ++h) {
        const int crow0 = r0 + h * 16 + kgrp * 4;
#pragma unroll
        for (int nt = 0; nt < 16; ++nt) {
#pragma unroll
            for (int q = 0; q < 4; ++q) {
                const int r = crow0 + q;
                if (r < N_NODES)
                    Hb[(size_t)r * DIM + nt * 16 + arow] = f2bf(acc[h][nt][q]);
            }
        }
    }
}

// ---------------- binning: build destination-CSR ----------------
__global__ __launch_bounds__(256)
void count_edges(const int* __restrict__ rows, int* __restrict__ cnt) {
    const int e = blockIdx.x * 256 + threadIdx.x;
    if (e < N_EDGES) atomicAdd(&cnt[rows[e]], 1);
}

__device__ __forceinline__ int block_excl_scan_256(int v, int* wsum, int* total) {
    const int lane = threadIdx.x & 63;
    const int wave = threadIdx.x >> 6;
    int x = v;
#pragma unroll
    for (int off = 1; off < 64; off <<= 1) {
        const int y = __shfl_up(x, off, 64);
        if (lane >= off) x += y;
    }
    if (lane == 63) wsum[wave] = x;
    __syncthreads();
    if (threadIdx.x == 0) {
        int s = 0;
#pragma unroll
        for (int w = 0; w < 4; ++w) { const int t = wsum[w]; wsum[w] = s; s += t; }
        *total = s;
    }
    __syncthreads();
    return wsum[wave] + x - v;
}

__global__ __launch_bounds__(256)
void scan_blocks(const int* __restrict__ cnt, int* __restrict__ offs,
                 int* __restrict__ bsum) {
    __shared__ int wsum[4];
    __shared__ int total;
    const int i = blockIdx.x * 256 + threadIdx.x;
    const int v = (i < N_NODES) ? cnt[i] : 0;
    const int excl = block_excl_scan_256(v, wsum, &total);
    if (i < N_NODES) offs[i] = excl;
    if (threadIdx.x == 0) bsum[blockIdx.x] = total;
}

#define NBLK_NODES 196   // ceil(50000/256)

__global__ __launch_bounds__(256)
void scan_top(int* __restrict__ bsum) {
    __shared__ int wsum[4];
    __shared__ int total;
    const int t = threadIdx.x;
    const int v = (t < NBLK_NODES) ? bsum[t] : 0;
    const int excl = block_excl_scan_256(v, wsum, &total);
    if (t < NBLK_NODES) bsum[t] = excl;
}

__global__ __launch_bounds__(256)
void scan_add(int* __restrict__ offs, const int* __restrict__ bsum) {
    const int i = blockIdx.x * 256 + threadIdx.x;
    if (i < N_NODES) offs[i] += bsum[blockIdx.x];
    if (i == 0) offs[N_NODES] = N_EDGES;
}

__global__ __launch_bounds__(256)
void fill_edges(const int* __restrict__ rows, const int* __restrict__ cols,
                const float* __restrict__ vals, const int* __restrict__ offs,
                int* __restrict__ cursor, int2* __restrict__ pe) {
    const int e = blockIdx.x * 256 + threadIdx.x;
    if (e >= N_EDGES) return;
    const int r = rows[e];
    const int p = atomicAdd(&cursor[r], 1);
    pe[offs[r] + p] = make_int2(cols[e], __float_as_int(vals[e]));
}

// ---------------- SpMM: out[r] = sum_e val * hidden_bf16[col] + b ----------------
__global__ __launch_bounds__(256)
void spmm(const unsigned short* __restrict__ Hb, const int* __restrict__ offs,
          const int2* __restrict__ pe, const float* __restrict__ bias,
          float* __restrict__ out) {
    const int row  = blockIdx.x * 4 + (threadIdx.x >> 6);
    const int lane = threadIdx.x & 63;
    if (row >= N_NODES) return;
    const int beg = offs[row];
    const int end = offs[row + 1];
    const unsigned lb = (unsigned)lane * 4;   // element offset within a hidden row
    float4 acc = make_float4(0.f, 0.f, 0.f, 0.f);
    int i = beg;
    // 8-deep: all gathers issued before any FMA (explicit regs, static indices)
    for (; i + 8 <= end; i += 8) {
        int2 e[8];
#pragma unroll
        for (int j = 0; j < 8; ++j) e[j] = pe[i + j];
        ushort4 h[8];
#pragma unroll
        for (int j = 0; j < 8; ++j)
            h[j] = *(const ushort4*)&Hb[((unsigned)e[j].x << 8) + lb];
#pragma unroll
        for (int j = 0; j < 8; ++j) {
            const float v = __int_as_float(e[j].y);
            acc.x += v * bf2f(h[j].x);
            acc.y += v * bf2f(h[j].y);
            acc.z += v * bf2f(h[j].z);
            acc.w += v * bf2f(h[j].w);
        }
    }
    for (; i < end; ++i) {
        const int2 e0 = pe[i];
        const ushort4 h0 = *(const ushort4*)&Hb[((unsigned)e0.x << 8) + lb];
        const float v0 = __int_as_float(e0.y);
        acc.x += v0 * bf2f(h0.x);
        acc.y += v0 * bf2f(h0.y);
        acc.z += v0 * bf2f(h0.z);
        acc.w += v0 * bf2f(h0.w);
    }
    const float4 bb = *(const float4*)&bias[lane * 4];
    acc.x += bb.x; acc.y += bb.y; acc.z += bb.z; acc.w += bb.w;
    *(float4*)&out[(size_t)row * DIM + lane * 4] = acc;
}

// ---------------- launch ----------------
extern "C" void kernel_launch(void* const* d_in, const int* in_sizes, int n_in,
                              void* d_out, int out_size, void* d_ws, size_t ws_size,
                              hipStream_t stream) {
    const float* x        = (const float*)d_in[0];
    const int*   adj_rows = (const int*)d_in[1];
    const int*   adj_cols = (const int*)d_in[2];
    const float* adj_vals = (const float*)d_in[3];
    const float* W        = (const float*)d_in[4];
    const float* b        = (const float*)d_in[5];
    float*       out      = (float*)d_out;

    char* ws = (char*)d_ws;
    size_t off = 0;
    auto alloc = [&](size_t bytes) {
        void* p = ws + off;
        off = (off + bytes + 255) & ~(size_t)255;
        return p;
    };
    unsigned short* hiddenb = (unsigned short*)alloc((size_t)N_NODES * DIM * sizeof(unsigned short)); // 25.6 MB
    unsigned short* Wt      = (unsigned short*)alloc((size_t)DIM * DIM * sizeof(unsigned short));     // 128 KB
    int*   offs    = (int*)  alloc((N_NODES + 1) * sizeof(int));
    int*   cntcur  = (int*)  alloc((size_t)2 * N_NODES * sizeof(int));  // cnt | cursor, contiguous
    int*   bsum    = (int*)  alloc(256 * sizeof(int));
    int2*  pe      = (int2*) alloc((size_t)N_EDGES * sizeof(int2));     // 6.4 MB
    int* cnt    = cntcur;
    int* cursor = cntcur + N_NODES;

    // prep: W -> W^T bf16
    wtrans<<<DIM, 256, 0, stream>>>(W, Wt);

    // GEMM: hidden = bf16(x) @ bf16(W)  (MFMA, 32-row strips)
    gemm_mfma<<<(STRIPS32 + 7) / 8, 512, 0, stream>>>(x, Wt, hiddenb);

    // binning
    hipMemsetAsync(cntcur, 0, (size_t)2 * N_NODES * sizeof(int), stream);
    count_edges<<<(N_EDGES + 255) / 256, 256, 0, stream>>>(adj_rows, cnt);
    scan_blocks<<<NBLK_NODES, 256, 0, stream>>>(cnt, offs, bsum);
    scan_top<<<1, 256, 0, stream>>>(bsum);
    scan_add<<<NBLK_NODES, 256, 0, stream>>>(offs, bsum);
    fill_edges<<<(N_EDGES + 255) / 256, 256, 0, stream>>>(
        adj_rows, adj_cols, adj_vals, offs, cursor, pe);

    // SpMM + bias
    spmm<<<(N_NODES + 3) / 4, 256, 0, stream>>>(hiddenb, offs, pe, b, out);
}

// Round 6
// 249.051 us; speedup vs baseline: 1.5958x; 1.0637x over previous
//
#include <hip/hip_runtime.h>

#define N_NODES 50000
#define N_EDGES 800000
#define DIM     256
#define STRIPS32 1563        // ceil(50000/32)
#define NBLK_NODES 196       // ceil(50000/256)
#define GEMM_BLOCKS 196      // ceil(1563/8)
#define COUNT_BLOCKS 782     // 782*1024 = 800768 >= N_EDGES
#define K2_BLOCKS (GEMM_BLOCKS + COUNT_BLOCKS)

typedef __attribute__((ext_vector_type(8))) short bf16x8;
typedef __attribute__((ext_vector_type(4))) float f32x4;

__device__ __forceinline__ unsigned short f2bf(float f) {
    unsigned u = __float_as_uint(f);
    unsigned r = (u + 0x7fffu + ((u >> 16) & 1u)) >> 16;
    return (unsigned short)r;
}
__device__ __forceinline__ float bf2f(unsigned short h) {
    return __uint_as_float((unsigned)h << 16);
}

// block-wide exclusive scan over 256 ints (wave64-based)
__device__ __forceinline__ int block_excl_scan_256(int v, int* wsum, int* total) {
    const int lane = threadIdx.x & 63;
    const int wave = threadIdx.x >> 6;
    int x = v;
#pragma unroll
    for (int off = 1; off < 64; off <<= 1) {
        const int y = __shfl_up(x, off, 64);
        if (lane >= off) x += y;
    }
    if (lane == 63) wsum[wave] = x;
    __syncthreads();
    if (threadIdx.x == 0) {
        int s = 0;
#pragma unroll
        for (int w = 0; w < 4; ++w) { const int t = wsum[w]; wsum[w] = s; s += t; }
        *total = s;
    }
    __syncthreads();
    return wsum[wave] + x - v;
}

// ---------------- K1: zero cnt/cursor + Wt[n][k] = bf16(W[k][n]) ----------------
__global__ __launch_bounds__(256)
void prep(const float* __restrict__ W, unsigned short* __restrict__ Wt,
          int* __restrict__ cntcur) {
    const int i = blockIdx.x * 256 + threadIdx.x;
    if (i < 2 * N_NODES) cntcur[i] = 0;
    if (blockIdx.x < DIM) {
        const int n = blockIdx.x, k = threadIdx.x;
        Wt[n * DIM + k] = f2bf(W[(size_t)k * DIM + n]);
    }
}

// ---------------- K2: GEMM blocks || count_edges blocks (independent work) ----------------
// GEMM: 128 KB LDS-resident swizzled W^T; each wave owns a 32-row strip of x,
// 2 A-fragments share every B ds_read, A loads software-pipelined.
__global__ __launch_bounds__(512, 2)
void gemm_count(const float* __restrict__ X, const unsigned short* __restrict__ Wt,
                unsigned short* __restrict__ Hb,
                const int* __restrict__ rows, int* __restrict__ cnt) {
    __shared__ unsigned short wl[DIM * DIM];   // 128 KB, [n][k] swizzled
    const int tid = threadIdx.x;

    if (blockIdx.x >= GEMM_BLOCKS) {
        // ---- edge-count blocks: 1024 edges each ----
        const int base = (blockIdx.x - GEMM_BLOCKS) * 1024;
        int e = base + tid;
        if (e < N_EDGES) atomicAdd(&cnt[rows[e]], 1);
        e += 512;
        if (e < N_EDGES) atomicAdd(&cnt[rows[e]], 1);
        return;
    }

    // ---- GEMM blocks ----
    {
        const uint4* src = (const uint4*)Wt;   // 8192 chunks of 16B
#pragma unroll
        for (int i = 0; i < 16; ++i) {
            const int c   = i * 512 + tid;
            const int row = c >> 5;
            const int kb  = (c & 31) * 16;
            const int dst = row * 512 + (kb ^ ((row & 7) << 4));
            *(uint4*)((char*)wl + dst) = src[c];
        }
    }
    __syncthreads();

    const int wid   = tid >> 6;
    const int lane  = tid & 63;
    const int strip = blockIdx.x * 8 + wid;
    if (strip >= STRIPS32) return;

    const int r0   = strip * 32;
    const int arow = lane & 15;
    const int kgrp = lane >> 4;
    const int ra = r0 + arow;
    const int rb = r0 + 16 + arow;
    const float* xa = X + (size_t)(ra < N_NODES ? ra : N_NODES - 1) * DIM + kgrp * 8;
    const float* xb = X + (size_t)(rb < N_NODES ? rb : N_NODES - 1) * DIM + kgrp * 8;

    f32x4 acc[2][16];
#pragma unroll
    for (int h = 0; h < 2; ++h)
#pragma unroll
        for (int nt = 0; nt < 16; ++nt) acc[h][nt] = f32x4{0.f, 0.f, 0.f, 0.f};

    const int swz = (arow & 7) << 4;

    float4 pa0 = *(const float4*)(xa);
    float4 pa1 = *(const float4*)(xa + 4);
    float4 pb0 = *(const float4*)(xb);
    float4 pb1 = *(const float4*)(xb + 4);

#pragma unroll
    for (int ks = 0; ks < 8; ++ks) {
        bf16x8 a0, a1;
        a0[0] = (short)f2bf(pa0.x); a0[1] = (short)f2bf(pa0.y);
        a0[2] = (short)f2bf(pa0.z); a0[3] = (short)f2bf(pa0.w);
        a0[4] = (short)f2bf(pa1.x); a0[5] = (short)f2bf(pa1.y);
        a0[6] = (short)f2bf(pa1.z); a0[7] = (short)f2bf(pa1.w);
        a1[0] = (short)f2bf(pb0.x); a1[1] = (short)f2bf(pb0.y);
        a1[2] = (short)f2bf(pb0.z); a1[3] = (short)f2bf(pb0.w);
        a1[4] = (short)f2bf(pb1.x); a1[5] = (short)f2bf(pb1.y);
        a1[6] = (short)f2bf(pb1.z); a1[7] = (short)f2bf(pb1.w);
        if (ks < 7) {
            pa0 = *(const float4*)(xa + (ks + 1) * 32);
            pa1 = *(const float4*)(xa + (ks + 1) * 32 + 4);
            pb0 = *(const float4*)(xb + (ks + 1) * 32);
            pb1 = *(const float4*)(xb + (ks + 1) * 32 + 4);
        }
        const int kb = ((ks * 32 + kgrp * 8) * 2) ^ swz;
#pragma unroll
        for (int nt = 0; nt < 16; ++nt) {
            const int n = nt * 16 + arow;
            const bf16x8 b = *(const bf16x8*)((const char*)wl + n * 512 + kb);
            acc[0][nt] = __builtin_amdgcn_mfma_f32_16x16x32_bf16(a0, b, acc[0][nt], 0, 0, 0);
            acc[1][nt] = __builtin_amdgcn_mfma_f32_16x16x32_bf16(a1, b, acc[1][nt], 0, 0, 0);
        }
    }

#pragma unroll
    for (int h = 0; h < 2; ++h) {
        const int crow0 = r0 + h * 16 + kgrp * 4;
#pragma unroll
        for (int nt = 0; nt < 16; ++nt) {
#pragma unroll
            for (int q = 0; q < 4; ++q) {
                const int r = crow0 + q;
                if (r < N_NODES)
                    Hb[(size_t)r * DIM + nt * 16 + arow] = f2bf(acc[h][nt][q]);
            }
        }
    }
}

// ---------------- K3: per-256-chunk exclusive scan; bsum[blk] = chunk total ----------------
__global__ __launch_bounds__(256)
void scan_blocks(const int* __restrict__ cnt, int* __restrict__ offs,
                 int* __restrict__ bsum) {
    __shared__ int wsum[4];
    __shared__ int total;
    const int i = blockIdx.x * 256 + threadIdx.x;
    const int v = (i < N_NODES) ? cnt[i] : 0;
    const int excl = block_excl_scan_256(v, wsum, &total);
    if (i < N_NODES) offs[i] = excl;
    if (threadIdx.x == 0) bsum[blockIdx.x] = total;
}

// ---------------- K4: fill dest-CSR; top-level prefix recomputed in-block ----------------
__global__ __launch_bounds__(256)
void fill_edges(const int* __restrict__ rows, const int* __restrict__ cols,
                const float* __restrict__ vals, const int* __restrict__ offs,
                const int* __restrict__ bsum, int* __restrict__ cursor,
                int2* __restrict__ pe) {
    __shared__ int wsum[4];
    __shared__ int total;
    __shared__ int P[256];
    {
        const int t = threadIdx.x;
        const int v = (t < NBLK_NODES) ? bsum[t] : 0;
        const int excl = block_excl_scan_256(v, wsum, &total);
        P[t] = excl;
    }
    __syncthreads();
    const int e = blockIdx.x * 256 + threadIdx.x;
    if (e >= N_EDGES) return;
    const int r = rows[e];
    const int p = atomicAdd(&cursor[r], 1);
    pe[offs[r] + P[r >> 8] + p] = make_int2(cols[e], __float_as_int(vals[e]));
}

// ---------------- K5: SpMM out[r] = sum val * hidden_bf16[col] + b ----------------
__global__ __launch_bounds__(256)
void spmm(const unsigned short* __restrict__ Hb, const int* __restrict__ offs,
          const int* __restrict__ bsum, const int2* __restrict__ pe,
          const float* __restrict__ bias, float* __restrict__ out) {
    __shared__ int wsum[4];
    __shared__ int total;
    __shared__ int P[256];
    {
        const int t = threadIdx.x;
        const int v = (t < NBLK_NODES) ? bsum[t] : 0;
        const int excl = block_excl_scan_256(v, wsum, &total);
        P[t] = excl;
    }
    __syncthreads();

    const int row  = blockIdx.x * 4 + (threadIdx.x >> 6);   // grid exactly 12500 -> row < 50000
    const int lane = threadIdx.x & 63;
    const int beg = offs[row] + P[row >> 8];
    const int end = (row + 1 == N_NODES) ? N_EDGES : (offs[row + 1] + P[(row + 1) >> 8]);
    const unsigned lb = (unsigned)lane * 4;
    float4 acc = make_float4(0.f, 0.f, 0.f, 0.f);
    int i = beg;
    for (; i + 8 <= end; i += 8) {
        int2 e[8];
#pragma unroll
        for (int j = 0; j < 8; ++j) e[j] = pe[i + j];
        ushort4 h[8];
#pragma unroll
        for (int j = 0; j < 8; ++j)
            h[j] = *(const ushort4*)&Hb[((unsigned)e[j].x << 8) + lb];
#pragma unroll
        for (int j = 0; j < 8; ++j) {
            const float v = __int_as_float(e[j].y);
            acc.x += v * bf2f(h[j].x);
            acc.y += v * bf2f(h[j].y);
            acc.z += v * bf2f(h[j].z);
            acc.w += v * bf2f(h[j].w);
        }
    }
    for (; i < end; ++i) {
        const int2 e0 = pe[i];
        const ushort4 h0 = *(const ushort4*)&Hb[((unsigned)e0.x << 8) + lb];
        const float v0 = __int_as_float(e0.y);
        acc.x += v0 * bf2f(h0.x);
        acc.y += v0 * bf2f(h0.y);
        acc.z += v0 * bf2f(h0.z);
        acc.w += v0 * bf2f(h0.w);
    }
    const float4 bb = *(const float4*)&bias[lane * 4];
    acc.x += bb.x; acc.y += bb.y; acc.z += bb.z; acc.w += bb.w;
    *(float4*)&out[(size_t)row * DIM + lane * 4] = acc;
}

// ---------------- launch ----------------
extern "C" void kernel_launch(void* const* d_in, const int* in_sizes, int n_in,
                              void* d_out, int out_size, void* d_ws, size_t ws_size,
                              hipStream_t stream) {
    const float* x        = (const float*)d_in[0];
    const int*   adj_rows = (const int*)d_in[1];
    const int*   adj_cols = (const int*)d_in[2];
    const float* adj_vals = (const float*)d_in[3];
    const float* W        = (const float*)d_in[4];
    const float* b        = (const float*)d_in[5];
    float*       out      = (float*)d_out;

    char* ws = (char*)d_ws;
    size_t off = 0;
    auto alloc = [&](size_t bytes) {
        void* p = ws + off;
        off = (off + bytes + 255) & ~(size_t)255;
        return p;
    };
    unsigned short* hiddenb = (unsigned short*)alloc((size_t)N_NODES * DIM * sizeof(unsigned short)); // 25.6 MB
    unsigned short* Wt      = (unsigned short*)alloc((size_t)DIM * DIM * sizeof(unsigned short));     // 128 KB
    int*   offs    = (int*)  alloc((size_t)N_NODES * sizeof(int));
    int*   cntcur  = (int*)  alloc((size_t)2 * N_NODES * sizeof(int));  // cnt | cursor
    int*   bsum    = (int*)  alloc(256 * sizeof(int));
    int2*  pe      = (int2*) alloc((size_t)N_EDGES * sizeof(int2));     // 6.4 MB
    int* cnt    = cntcur;
    int* cursor = cntcur + N_NODES;

    // K1: zero + W^T bf16
    prep<<<(2 * N_NODES + 255) / 256, 256, 0, stream>>>(W, Wt, cntcur);

    // K2: GEMM || edge count
    gemm_count<<<K2_BLOCKS, 512, 0, stream>>>(x, Wt, hiddenb, adj_rows, cnt);

    // K3: per-chunk scan
    scan_blocks<<<NBLK_NODES, 256, 0, stream>>>(cnt, offs, bsum);

    // K4: fill dest-CSR
    fill_edges<<<(N_EDGES + 255) / 256, 256, 0, stream>>>(
        adj_rows, adj_cols, adj_vals, offs, bsum, cursor, pe);

    // K5: SpMM + bias
    spmm<<<N_NODES / 4, 256, 0, stream>>>(hiddenb, offs, bsum, pe, b, out);
}

// Round 7
// 245.300 us; speedup vs baseline: 1.6202x; 1.0153x over previous
//
#include <hip/hip_runtime.h>

#define N_NODES 50000
#define N_EDGES 800000
#define DIM     256
#define STRIPS32 1563        // ceil(50000/32)
#define NBLK_NODES 196       // ceil(50000/256)
#define GEMM_BLOCKS 196      // ceil(1563/8)

typedef __attribute__((ext_vector_type(8))) short bf16x8;
typedef __attribute__((ext_vector_type(4))) float f32x4;

__device__ __forceinline__ unsigned short f2bf(float f) {
    unsigned u = __float_as_uint(f);
    unsigned r = (u + 0x7fffu + ((u >> 16) & 1u)) >> 16;
    return (unsigned short)r;
}
__device__ __forceinline__ float bf2f(unsigned short h) {
    return __uint_as_float((unsigned)h << 16);
}

// block-wide exclusive scan over 256 ints (wave64-based)
__device__ __forceinline__ int block_excl_scan_256(int v, int* wsum, int* total) {
    const int lane = threadIdx.x & 63;
    const int wave = threadIdx.x >> 6;
    int x = v;
#pragma unroll
    for (int off = 1; off < 64; off <<= 1) {
        const int y = __shfl_up(x, off, 64);
        if (lane >= off) x += y;
    }
    if (lane == 63) wsum[wave] = x;
    __syncthreads();
    if (threadIdx.x == 0) {
        int s = 0;
#pragma unroll
        for (int w = 0; w < 4; ++w) { const int t = wsum[w]; wsum[w] = s; s += t; }
        *total = s;
    }
    __syncthreads();
    return wsum[wave] + x - v;
}

// ---------------- K1: zero cnt + Wt[n][k] = bf16(W[k][n]) ----------------
__global__ __launch_bounds__(256)
void prep(const float* __restrict__ W, unsigned short* __restrict__ Wt,
          int* __restrict__ cnt) {
    const int i = blockIdx.x * 256 + threadIdx.x;
    if (i < N_NODES) cnt[i] = 0;
    const int n = blockIdx.x, k = threadIdx.x;   // grid is exactly DIM=256 blocks
    Wt[n * DIM + k] = f2bf(W[(size_t)k * DIM + n]);
}

// ---------------- K2: GEMM hidden_bf16 = bf16(x) @ bf16(W) via MFMA ----------------
__global__ __launch_bounds__(512, 2)
void gemm_mfma(const float* __restrict__ X, const unsigned short* __restrict__ Wt,
               unsigned short* __restrict__ Hb) {
    __shared__ unsigned short wl[DIM * DIM];   // 128 KB, [n][k] swizzled
    const int tid = threadIdx.x;
    {
        const uint4* src = (const uint4*)Wt;   // 8192 chunks of 16B
#pragma unroll
        for (int i = 0; i < 16; ++i) {
            const int c   = i * 512 + tid;
            const int row = c >> 5;
            const int kb  = (c & 31) * 16;
            const int dst = row * 512 + (kb ^ ((row & 7) << 4));
            *(uint4*)((char*)wl + dst) = src[c];
        }
    }
    __syncthreads();

    const int wid   = tid >> 6;
    const int lane  = tid & 63;
    const int strip = blockIdx.x * 8 + wid;
    if (strip >= STRIPS32) return;

    const int r0   = strip * 32;
    const int arow = lane & 15;
    const int kgrp = lane >> 4;
    const int ra = r0 + arow;
    const int rb = r0 + 16 + arow;
    const float* xa = X + (size_t)(ra < N_NODES ? ra : N_NODES - 1) * DIM + kgrp * 8;
    const float* xb = X + (size_t)(rb < N_NODES ? rb : N_NODES - 1) * DIM + kgrp * 8;

    f32x4 acc[2][16];
#pragma unroll
    for (int h = 0; h < 2; ++h)
#pragma unroll
        for (int nt = 0; nt < 16; ++nt) acc[h][nt] = f32x4{0.f, 0.f, 0.f, 0.f};

    const int swz = (arow & 7) << 4;

    float4 pa0 = *(const float4*)(xa);
    float4 pa1 = *(const float4*)(xa + 4);
    float4 pb0 = *(const float4*)(xb);
    float4 pb1 = *(const float4*)(xb + 4);

#pragma unroll
    for (int ks = 0; ks < 8; ++ks) {
        bf16x8 a0, a1;
        a0[0] = (short)f2bf(pa0.x); a0[1] = (short)f2bf(pa0.y);
        a0[2] = (short)f2bf(pa0.z); a0[3] = (short)f2bf(pa0.w);
        a0[4] = (short)f2bf(pa1.x); a0[5] = (short)f2bf(pa1.y);
        a0[6] = (short)f2bf(pa1.z); a0[7] = (short)f2bf(pa1.w);
        a1[0] = (short)f2bf(pb0.x); a1[1] = (short)f2bf(pb0.y);
        a1[2] = (short)f2bf(pb0.z); a1[3] = (short)f2bf(pb0.w);
        a1[4] = (short)f2bf(pb1.x); a1[5] = (short)f2bf(pb1.y);
        a1[6] = (short)f2bf(pb1.z); a1[7] = (short)f2bf(pb1.w);
        if (ks < 7) {
            pa0 = *(const float4*)(xa + (ks + 1) * 32);
            pa1 = *(const float4*)(xa + (ks + 1) * 32 + 4);
            pb0 = *(const float4*)(xb + (ks + 1) * 32);
            pb1 = *(const float4*)(xb + (ks + 1) * 32 + 4);
        }
        const int kb = ((ks * 32 + kgrp * 8) * 2) ^ swz;
#pragma unroll
        for (int nt = 0; nt < 16; ++nt) {
            const int n = nt * 16 + arow;
            const bf16x8 b = *(const bf16x8*)((const char*)wl + n * 512 + kb);
            acc[0][nt] = __builtin_amdgcn_mfma_f32_16x16x32_bf16(a0, b, acc[0][nt], 0, 0, 0);
            acc[1][nt] = __builtin_amdgcn_mfma_f32_16x16x32_bf16(a1, b, acc[1][nt], 0, 0, 0);
        }
    }

#pragma unroll
    for (int h = 0; h < 2; ++h) {
        const int crow0 = r0 + h * 16 + kgrp * 4;
#pragma unroll
        for (int nt = 0; nt < 16; ++nt) {
#pragma unroll
            for (int q = 0; q < 4; ++q) {
                const int r = crow0 + q;
                if (r < N_NODES)
                    Hb[(size_t)r * DIM + nt * 16 + arow] = f2bf(acc[h][nt][q]);
            }
        }
    }
}

// ---------------- K3: count + per-edge rank (one atomic pass total) ----------------
__global__ __launch_bounds__(256)
void count_rank(const int* __restrict__ rows, int* __restrict__ cnt,
                unsigned short* __restrict__ rank) {
    const int e0 = (blockIdx.x * 256 + threadIdx.x) * 4;
    if (e0 >= N_EDGES) return;     // N_EDGES % 4 == 0
    const int4 r4 = *(const int4*)&rows[e0];
    ushort4 rk;
    rk.x = (unsigned short)atomicAdd(&cnt[r4.x], 1);
    rk.y = (unsigned short)atomicAdd(&cnt[r4.y], 1);
    rk.z = (unsigned short)atomicAdd(&cnt[r4.z], 1);
    rk.w = (unsigned short)atomicAdd(&cnt[r4.w], 1);
    *(ushort4*)&rank[e0] = rk;
}

// ---------------- K4: per-256-chunk exclusive scan; bsum[blk] = chunk total ----------------
__global__ __launch_bounds__(256)
void scan_blocks(const int* __restrict__ cnt, int* __restrict__ offs,
                 int* __restrict__ bsum) {
    __shared__ int wsum[4];
    __shared__ int total;
    const int i = blockIdx.x * 256 + threadIdx.x;
    const int v = (i < N_NODES) ? cnt[i] : 0;
    const int excl = block_excl_scan_256(v, wsum, &total);
    if (i < N_NODES) offs[i] = excl;
    if (threadIdx.x == 0) bsum[blockIdx.x] = total;
}

// ---------------- K5: fill dest-CSR (NO atomics; rank precomputed) ----------------
__global__ __launch_bounds__(256)
void fill_edges(const int* __restrict__ rows, const int* __restrict__ cols,
                const float* __restrict__ vals, const int* __restrict__ offs,
                const int* __restrict__ bsum, const unsigned short* __restrict__ rank,
                int2* __restrict__ pe) {
    __shared__ int wsum[4];
    __shared__ int total;
    __shared__ int P[256];
    {
        const int t = threadIdx.x;
        const int v = (t < NBLK_NODES) ? bsum[t] : 0;
        const int excl = block_excl_scan_256(v, wsum, &total);
        P[t] = excl;
    }
    __syncthreads();
    const int e = blockIdx.x * 256 + threadIdx.x;
    if (e >= N_EDGES) return;
    const int r = rows[e];
    pe[offs[r] + P[r >> 8] + rank[e]] = make_int2(cols[e], __float_as_int(vals[e]));
}

// ---------------- K6: SpMM out[r] = sum val * hidden_bf16[col] + b ----------------
__global__ __launch_bounds__(256)
void spmm(const unsigned short* __restrict__ Hb, const int* __restrict__ offs,
          const int* __restrict__ bsum, const int2* __restrict__ pe,
          const float* __restrict__ bias, float* __restrict__ out) {
    __shared__ int wsum[4];
    __shared__ int total;
    __shared__ int P[256];
    {
        const int t = threadIdx.x;
        const int v = (t < NBLK_NODES) ? bsum[t] : 0;
        const int excl = block_excl_scan_256(v, wsum, &total);
        P[t] = excl;
    }
    __syncthreads();

    const int row  = blockIdx.x * 4 + (threadIdx.x >> 6);   // grid = 12500 -> row < 50000
    const int lane = threadIdx.x & 63;
    const int beg = offs[row] + P[row >> 8];
    const int end = (row + 1 == N_NODES) ? N_EDGES : (offs[row + 1] + P[(row + 1) >> 8]);
    const unsigned lb = (unsigned)lane * 4;
    float4 acc = make_float4(0.f, 0.f, 0.f, 0.f);
    int i = beg;
    for (; i + 8 <= end; i += 8) {
        int2 e[8];
#pragma unroll
        for (int j = 0; j < 8; ++j) e[j] = pe[i + j];
        ushort4 h[8];
#pragma unroll
        for (int j = 0; j < 8; ++j)
            h[j] = *(const ushort4*)&Hb[((unsigned)e[j].x << 8) + lb];
#pragma unroll
        for (int j = 0; j < 8; ++j) {
            const float v = __int_as_float(e[j].y);
            acc.x += v * bf2f(h[j].x);
            acc.y += v * bf2f(h[j].y);
            acc.z += v * bf2f(h[j].z);
            acc.w += v * bf2f(h[j].w);
        }
    }
    for (; i < end; ++i) {
        const int2 e0 = pe[i];
        const ushort4 h0 = *(const ushort4*)&Hb[((unsigned)e0.x << 8) + lb];
        const float v0 = __int_as_float(e0.y);
        acc.x += v0 * bf2f(h0.x);
        acc.y += v0 * bf2f(h0.y);
        acc.z += v0 * bf2f(h0.z);
        acc.w += v0 * bf2f(h0.w);
    }
    const float4 bb = *(const float4*)&bias[lane * 4];
    acc.x += bb.x; acc.y += bb.y; acc.z += bb.z; acc.w += bb.w;
    *(float4*)&out[(size_t)row * DIM + lane * 4] = acc;
}

// ---------------- launch ----------------
extern "C" void kernel_launch(void* const* d_in, const int* in_sizes, int n_in,
                              void* d_out, int out_size, void* d_ws, size_t ws_size,
                              hipStream_t stream) {
    const float* x        = (const float*)d_in[0];
    const int*   adj_rows = (const int*)d_in[1];
    const int*   adj_cols = (const int*)d_in[2];
    const float* adj_vals = (const float*)d_in[3];
    const float* W        = (const float*)d_in[4];
    const float* b        = (const float*)d_in[5];
    float*       out      = (float*)d_out;

    char* ws = (char*)d_ws;
    size_t off = 0;
    auto alloc = [&](size_t bytes) {
        void* p = ws + off;
        off = (off + bytes + 255) & ~(size_t)255;
        return p;
    };
    unsigned short* hiddenb = (unsigned short*)alloc((size_t)N_NODES * DIM * sizeof(unsigned short)); // 25.6 MB
    unsigned short* Wt      = (unsigned short*)alloc((size_t)DIM * DIM * sizeof(unsigned short));     // 128 KB
    int*            offs    = (int*)alloc((size_t)N_NODES * sizeof(int));
    int*            cnt     = (int*)alloc((size_t)N_NODES * sizeof(int));
    int*            bsum    = (int*)alloc(256 * sizeof(int));
    unsigned short* rank    = (unsigned short*)alloc((size_t)N_EDGES * sizeof(unsigned short)); // 1.6 MB
    int2*           pe      = (int2*)alloc((size_t)N_EDGES * sizeof(int2));                     // 6.4 MB

    // K1: zero cnt + W^T bf16
    prep<<<DIM, 256, 0, stream>>>(W, Wt, cnt);

    // K2: GEMM (MFMA, LDS-resident W^T)
    gemm_mfma<<<GEMM_BLOCKS, 512, 0, stream>>>(x, Wt, hiddenb);

    // K3: count + rank (single atomic pass)
    count_rank<<<(N_EDGES / 4 + 255) / 256, 256, 0, stream>>>(adj_rows, cnt, rank);

    // K4: per-chunk scan
    scan_blocks<<<NBLK_NODES, 256, 0, stream>>>(cnt, offs, bsum);

    // K5: fill dest-CSR (no atomics)
    fill_edges<<<(N_EDGES + 255) / 256, 256, 0, stream>>>(
        adj_rows, adj_cols, adj_vals, offs, bsum, rank, pe);

    // K6: SpMM + bias
    spmm<<<N_NODES / 4, 256, 0, stream>>>(hiddenb, offs, bsum, pe, b, out);
}